// Round 3
// baseline (166.403 us; speedup 1.0000x reference)
//
#include <hip/hip_runtime.h>
#include <stdint.h>

// ---- types ----
typedef __attribute__((ext_vector_type(4))) float   f4;
typedef __attribute__((ext_vector_type(8))) short   short8;   // 8 x bf16 (MFMA A/B frag)
typedef __attribute__((ext_vector_type(4))) float   floatx4;  // MFMA C/D frag
typedef __attribute__((ext_vector_type(4))) unsigned int u32x4;

#define LN2F 0.6931471805599453f

// Problem constants
#define BB 65536
#define SS 512
#define DD 100
// K padded to 128 (4 k-steps of 32 for mfma 16x16x32 bf16)

__device__ __forceinline__ unsigned short f2bf(float f) {
  union { float f; unsigned int u; } v; v.f = f;
  unsigned int u = v.u;
  u += 0x7fffu + ((u >> 16) & 1u);   // RNE
  return (unsigned short)(u >> 16);
}
__device__ __forceinline__ u32x4 pack8(f4 a, f4 b) {
  u32x4 r;
  r.x = (unsigned int)f2bf(a[0]) | ((unsigned int)f2bf(a[1]) << 16);
  r.y = (unsigned int)f2bf(a[2]) | ((unsigned int)f2bf(a[3]) << 16);
  r.z = (unsigned int)f2bf(b[0]) | ((unsigned int)f2bf(b[1]) << 16);
  r.w = (unsigned int)f2bf(b[2]) | ((unsigned int)f2bf(b[3]) << 16);
  return r;
}
// numerically stable softplus(x) = log(1+e^x)
__device__ __forceinline__ float softplus_full(float x) {
  return fmaxf(x, 0.f) + log1pf(expf(-fabsf(x)));
}
// LDS-visibility barrier that does NOT drain vmcnt: in-flight register
// global-loads legally cross it (T14 async-stage prerequisite). The asm
// memory clobber pins load ISSUE order (loads before it cannot sink below).
__device__ __forceinline__ void lds_barrier() {
  asm volatile("s_waitcnt lgkmcnt(0)" ::: "memory");
  __builtin_amdgcn_s_barrier();
}

// ---------------------------------------------------------------------------
// Kernel 1: gather + convert neg rows into MFMA B-fragment tiled layout in ws.
// Layout: 16B unit index = (sgroup*4 + kstep)*64 + (s&15) + 16*kquad
// Also zero-inits out[0]. Junk lanes redirected into the row interior so each
// 400B row fetches exactly its 4-cacheline span.
// ---------------------------------------------------------------------------
__global__ __launch_bounds__(256) void negprep_k(
    const float* __restrict__ tail_table, const int* __restrict__ neg_idx,
    u32x4* __restrict__ nws, float* __restrict__ out) {
  if (blockIdx.x == 0 && threadIdx.x == 0) out[0] = 0.f;
  int tid = blockIdx.x * 256 + threadIdx.x;          // 32 blocks -> 8192 threads
  int s = tid >> 4, kg = tid & 15, k0 = kg * 8;      // 16 threads per s-row
  int nrow = neg_idx[s];
  const float* np = tail_table + (size_t)nrow * DD;  // rows 400B, 16B aligned
  const int aoff = (kg <= 12) ? k0     : 0;
  const int boff = (kg <  12) ? k0 + 4 : 4;
  f4 a = *(const f4*)(np + aoff);
  f4 b = *(const f4*)(np + boff);
  if (kg > 12)  a = (f4){0.f,0.f,0.f,0.f};
  if (kg >= 12) b = (f4){0.f,0.f,0.f,0.f};
  nws[((s >> 4) * 4 + (kg >> 2)) * 64 + (s & 15) + 16 * (kg & 3)] = pack8(a, b);
}

// ---------------------------------------------------------------------------
// Kernel 2: fused pipelined main. 1024 blocks x 256 thr; block owns 64 b-rows
// (2 half-tiles of 32) x all 512 s. All 16 gather dwordx4 issue up front
// (R0's proven max-MLP batched gather, __launch_bounds__(256,4) for 128
// VGPRs); then: pack t0 -> buf0 (waits only t0's 8 loads), lds_barrier (no
// vmcnt drain!), MFMA t0 WHILE t1's loads are still in flight, pack t1 ->
// buf1 (compiler vmcnt-waits at first use), lds_barrier, MFMA t1. This hides
// the gather tail (the slowest of each block's random row fetches) under the
// half-tile-0 matmul, which R0 serialized behind a full-tile barrier.
// B-frag L2 traffic identical to R0 (afr[2][4] per half, bfr re-read 2x).
// ---------------------------------------------------------------------------
__global__ __launch_bounds__(256, 4) void keg_pipe(
    const float* __restrict__ head_table, const float* __restrict__ tail_table,
    const float* __restrict__ rel_vec,   const float* __restrict__ rel_bias,
    const int* __restrict__ head_idx,    const int* __restrict__ tail_idx,
    const u32x4* __restrict__ nws,       float* __restrict__ out) {
  __shared__ u32x4 exA4[2][512];              // 2 bufs x (32 rows x 128 k): 16KB
  __shared__ __align__(16) float bias_s[2][32];
  __shared__ float red[4];

  const int t = threadIdx.x;
  const int kg = t & 15, grp = t >> 4, k0 = kg * 8;
  const int bbase = blockIdx.x * 64;

  // rel fragments (rel_vec has exactly 100 floats -> conditional)
  f4 ra = {0,0,0,0}, rb = {0,0,0,0};
  if (kg <= 12) ra = *(const f4*)(rel_vec + k0);
  if (kg <  12) rb = *(const f4*)(rel_vec + k0 + 4);
  // junk-lane offsets redirected into the row: fetch span stays 4 lines/row
  const int aoff = (kg <= 12) ? k0     : 0;
  const int boff = (kg <  12) ? k0 + 4 : 4;

  // ---- addresses for both half-tiles (2 pairs per 16-lane group each) ----
  const float* hp[2][2]; const float* tp[2][2]; float biasv[2][2];
  #pragma unroll
  for (int T = 0; T < 2; ++T)
    #pragma unroll
    for (int p = 0; p < 2; ++p) {
      int R = bbase + T * 32 + p * 16 + grp;   // row-in-tile = p*16+grp
      hp[T][p] = head_table + (size_t)head_idx[R] * DD;
      int trow = tail_idx[R];
      tp[T][p] = tail_table + (size_t)trow * DD;
      biasv[T][p] = rel_bias[trow];            // 16 lanes same addr
    }

  // ---- issue ALL 16 gather dwordx4 back-to-back (t0 first) ----
  f4 ha[2][2], hb[2][2], ta[2][2], tb[2][2];
  #pragma unroll
  for (int T = 0; T < 2; ++T)
    #pragma unroll
    for (int p = 0; p < 2; ++p) {
      // unconditional: offsets stay inside the table (junk redirected in-row)
      ha[T][p] = *(const f4*)(hp[T][p] + aoff);
      hb[T][p] = *(const f4*)(hp[T][p] + boff);
      ta[T][p] = *(const f4*)(tp[T][p] + aoff);
      tb[T][p] = *(const f4*)(tp[T][p] + boff);
    }

  const int w = t >> 6, lane = t & 63, quad = lane >> 4;
  const short8* nf = (const short8*)nws;
  float pos_acc = 0.f, nacc = 0.f;

  // ---- pack half-tile T into buf T (+ fp32 pos-loss) ----
#define PACK_TILE(T)                                                          \
  {                                                                           \
    _Pragma("unroll")                                                         \
    for (int p = 0; p < 2; ++p) {                                             \
      f4 e0 = ha[T][p] + ra, e1 = hb[T][p] + rb;                              \
      if (kg > 12)  e0 = (f4){0.f,0.f,0.f,0.f};                               \
      if (kg >= 12) e1 = (f4){0.f,0.f,0.f,0.f};                               \
      exA4[T][(p * 4 + (kg >> 2)) * 64 + grp + 16 * (kg & 3)] = pack8(e0, e1);\
      float d = e0[0]*ta[T][p][0] + e0[1]*ta[T][p][1] + e0[2]*ta[T][p][2]     \
              + e0[3]*ta[T][p][3] + e1[0]*tb[T][p][0] + e1[1]*tb[T][p][1]     \
              + e1[2]*tb[T][p][2] + e1[3]*tb[T][p][3];                        \
      d += __shfl_xor(d, 1); d += __shfl_xor(d, 2);                           \
      d += __shfl_xor(d, 4); d += __shfl_xor(d, 8);                           \
      if (kg == 0) {                                                          \
        bias_s[T][p * 16 + grp] = biasv[T][p];                                \
        pos_acc += softplus_full(-(d + biasv[T][p]));                         \
      }                                                                       \
    }                                                                         \
  }

  // ---- MFMA over buf B: proven R0 half-structure (8 s-groups per wave) ----
#define MFMA_STAGE(B)                                                         \
  {                                                                           \
    const short8* exAs = (const short8*)exA4[B];                              \
    short8 afr[2][4];                                                         \
    float  br[2][4];                                                          \
    _Pragma("unroll")                                                         \
    for (int m = 0; m < 2; ++m) {                                             \
      _Pragma("unroll")                                                       \
      for (int ks = 0; ks < 4; ++ks) afr[m][ks] = exAs[(m * 4 + ks) * 64 + lane]; \
      _Pragma("unroll")                                                       \
      for (int r = 0; r < 4; ++r)   br[m][r]  = bias_s[B][m * 16 + quad * 4 + r]; \
    }                                                                         \
    _Pragma("unroll 2")                                                       \
    for (int g = 0; g < 8; ++g) {                                             \
      int ng = w * 8 + g;                                                     \
      short8 bfr[4];                                                          \
      _Pragma("unroll")                                                       \
      for (int ks = 0; ks < 4; ++ks)                                          \
        bfr[ks] = nf[(ng * 4 + ks) * 64 + lane];   /* L2-hot */               \
      floatx4 acc[2];                                                         \
      _Pragma("unroll")                                                       \
      for (int m = 0; m < 2; ++m) {                /* bias folded into C */   \
        floatx4 c; c[0]=br[m][0]; c[1]=br[m][1]; c[2]=br[m][2]; c[3]=br[m][3];\
        acc[m] = c;                                                           \
      }                                                                       \
      _Pragma("unroll")                                                       \
      for (int ks = 0; ks < 4; ++ks)                                          \
        _Pragma("unroll")                                                     \
        for (int m = 0; m < 2; ++m)                                           \
          acc[m] = __builtin_amdgcn_mfma_f32_16x16x32_bf16(afr[m][ks], bfr[ks], acc[m], 0, 0, 0); \
      float s1 = 0.f, s2 = 0.f, gmax = 0.f;                                   \
      _Pragma("unroll")                                                       \
      for (int m = 0; m < 2; ++m)                                             \
        _Pragma("unroll")                                                     \
        for (int r = 0; r < 4; ++r) {                                         \
          float x = acc[m][r];                                                \
          s1 += x;                                                            \
          s2 = fmaf(x, x, s2);                                                \
          gmax = fmaxf(gmax, fabsf(x));                                       \
        }                                                                     \
      if (__ballot(gmax < 0.03f) == ~0ULL) {                                  \
        /* deg-2 Taylor softplus: ln2 + x/2 + x^2/8, |err|<5e-9 for |x|<.03 */\
        nacc += fmaf(s1, 0.5f, fmaf(s2, 0.125f, 8.f * LN2F));                 \
      } else {                                                                \
        _Pragma("unroll")                                                     \
        for (int m = 0; m < 2; ++m)                                           \
          _Pragma("unroll")                                                   \
          for (int r = 0; r < 4; ++r)                                         \
            nacc += softplus_full(acc[m][r]);                                 \
      }                                                                       \
    }                                                                         \
  }

  PACK_TILE(0)          // waits only t0's 8 loads (vmcnt(8) remain in flight)
  lds_barrier();        // LDS visibility only -- t1 loads stay in flight
  MFMA_STAGE(0)         // matmul t0 hides t1's gather tail
  PACK_TILE(1)          // compiler vmcnt-waits t1 data at first use here
  lds_barrier();
  MFMA_STAGE(1)

#undef PACK_TILE
#undef MFMA_STAGE

  // ---- block reduce -> atomic accumulate (exact pow2 1/BB scale) ----
  float tot = nacc + pos_acc;
  #pragma unroll
  for (int off = 32; off; off >>= 1) tot += __shfl_down(tot, off);
  if (lane == 0) red[w] = tot;
  __syncthreads();
  if (t == 0)
    atomicAdd(out, (red[0] + red[1] + red[2] + red[3]) * (1.0f / (float)BB));
}

extern "C" void kernel_launch(void* const* d_in, const int* in_sizes, int n_in,
                              void* d_out, int out_size, void* d_ws, size_t ws_size,
                              hipStream_t stream) {
  const float* head_table = (const float*)d_in[0];
  const float* tail_table = (const float*)d_in[1];
  const float* rel_vec    = (const float*)d_in[2];
  const float* rel_bias   = (const float*)d_in[3];
  const int*   head_idx   = (const int*)d_in[4];
  const int*   tail_idx   = (const int*)d_in[5];
  const int*   neg_idx    = (const int*)d_in[6];
  float* out = (float*)d_out;

  u32x4* nws = (u32x4*)d_ws;                 // 512 x 128 bf16 = 131072 B

  negprep_k<<<32, 256, 0, stream>>>(tail_table, neg_idx, nws, out);
  keg_pipe<<<1024, 256, 0, stream>>>(head_table, tail_table, rel_vec, rel_bias,
                                     head_idx, tail_idx, (const u32x4*)nws, out);
}

// Round 6
// 157.428 us; speedup vs baseline: 1.0570x; 1.0570x over previous
//
#include <hip/hip_runtime.h>
#include <stdint.h>

// ---- types ----
typedef __attribute__((ext_vector_type(4))) float   f4;
typedef __attribute__((ext_vector_type(8))) short   short8;   // 8 x bf16 (MFMA A/B frag)
typedef __attribute__((ext_vector_type(4))) float   floatx4;  // MFMA C/D frag
typedef __attribute__((ext_vector_type(4))) unsigned int u32x4;

#define LN2F 0.6931471805599453f

// Problem constants
#define BB 65536
#define SS 512
#define DD 100
// K padded to 128 (4 k-steps of 32 for mfma 16x16x32 bf16)

__device__ __forceinline__ unsigned short f2bf(float f) {
  union { float f; unsigned int u; } v; v.f = f;
  unsigned int u = v.u;
  u += 0x7fffu + ((u >> 16) & 1u);   // RNE
  return (unsigned short)(u >> 16);
}
__device__ __forceinline__ u32x4 pack8(f4 a, f4 b) {
  u32x4 r;
  r.x = (unsigned int)f2bf(a[0]) | ((unsigned int)f2bf(a[1]) << 16);
  r.y = (unsigned int)f2bf(a[2]) | ((unsigned int)f2bf(a[3]) << 16);
  r.z = (unsigned int)f2bf(b[0]) | ((unsigned int)f2bf(b[1]) << 16);
  r.w = (unsigned int)f2bf(b[2]) | ((unsigned int)f2bf(b[3]) << 16);
  return r;
}
// numerically stable softplus(x) = log(1+e^x)
__device__ __forceinline__ float softplus_full(float x) {
  return fmaxf(x, 0.f) + log1pf(expf(-fabsf(x)));
}

// ---------------------------------------------------------------------------
// Kernel 1: gather + convert neg rows into MFMA B-fragment tiled layout in ws.
// Layout: 16B unit index = (sgroup*4 + kstep)*64 + (s&15) + 16*kquad
// Also zero-inits out[0]. Junk lanes (kg>=13 a, kg>=12 b) are redirected into
// the row interior so each 400B row fetches exactly its 4-cacheline span
// (400B rows start at offsets mod 128 <= 112; 400+112=512), not 5 lines.
// ---------------------------------------------------------------------------
__global__ __launch_bounds__(256) void negprep_k(
    const float* __restrict__ tail_table, const int* __restrict__ neg_idx,
    u32x4* __restrict__ nws, float* __restrict__ out) {
  if (blockIdx.x == 0 && threadIdx.x == 0) out[0] = 0.f;
  int tid = blockIdx.x * 256 + threadIdx.x;          // 32 blocks -> 8192 threads
  int s = tid >> 4, kg = tid & 15, k0 = kg * 8;      // 16 threads per s-row
  int nrow = neg_idx[s];
  const float* np = tail_table + (size_t)nrow * DD;  // rows 400B, 16B aligned
  const int aoff = (kg <= 12) ? k0     : 0;          // junk -> row interior
  const int boff = (kg <  12) ? k0 + 4 : 4;
  f4 a = *(const f4*)(np + aoff);
  f4 b = *(const f4*)(np + boff);
  if (kg > 12)  a = (f4){0.f,0.f,0.f,0.f};
  if (kg >= 12) b = (f4){0.f,0.f,0.f,0.f};
  nws[((s >> 4) * 4 + (kg >> 2)) * 64 + (s & 15) + 16 * (kg & 3)] = pack8(a, b);
}

// ---------------------------------------------------------------------------
// Kernel 2: fused main — EXACT R0 structure (best measured config) with the
// only delta being the junk-lane in-row redirect (2 cndmask on offsets,
// executed fine in R1's kernel; cuts gather fetch ~51MB -> 44.5MB measured).
// 1024 blocks x 256 thr; block owns 64 b-rows x all 512 s. Stage 1: every
// thread issues 16 unconditional global_load_dwordx4 (4 rows x head+tail)
// before any consumption; __launch_bounds__(256,4) gives the allocator a
// 128-VGPR budget. Pos-loss in fp32 during the gather. Neg matmul:
// register-lean 2-half loop, per-group ballot-guarded Taylor epilogue with
// inline unrolled exact fallback (no scratch anywhere).
// NOTE: the amdgpu_waves_per_eu(4,4) exact-pin experiment (R4/R5) hit two
// consecutive container failures with no counters; attribute removed as the
// only untested element. This round must also reveal keg_main's true
// VGPR/WRITE_SIZE in its best config (never yet profiled).
// ---------------------------------------------------------------------------
__global__ __launch_bounds__(256, 4) void keg_main(
    const float* __restrict__ head_table, const float* __restrict__ tail_table,
    const float* __restrict__ rel_vec,   const float* __restrict__ rel_bias,
    const int* __restrict__ head_idx,    const int* __restrict__ tail_idx,
    const u32x4* __restrict__ nws,       float* __restrict__ out) {
  __shared__ u32x4 exA4[1024];   // 64 rows x 128 k, A-frag tiled: 16KB
  __shared__ __align__(16) float bias_s[64];
  __shared__ float red[4];

  const int t = threadIdx.x;
  const int kg = t & 15, rid = t >> 4, k0 = kg * 8;
  const int bbase = blockIdx.x * 64;

  // rel fragments (masked; rel_vec has exactly 100 floats -> conditional)
  f4 ra = {0,0,0,0}, rb = {0,0,0,0};
  if (kg <= 12) ra = *(const f4*)(rel_vec + k0);       // kg==12: rel[96..99]
  if (kg <  12) rb = *(const f4*)(rel_vec + k0 + 4);

  // junk-lane offsets redirected into the row: fetch span stays 4 lines/row
  const int aoff = (kg <= 12) ? k0     : 0;
  const int boff = (kg <  12) ? k0 + 4 : 4;

  // ---- batched gather: addresses first, then 16 dwordx4 back-to-back ----
  const float* hp[4]; const float* tp[4];
  float biasv[4];
  #pragma unroll
  for (int p = 0; p < 4; ++p) {
    int R = bbase + p * 16 + rid;
    hp[p] = head_table + (size_t)head_idx[R] * DD;
    int trow = tail_idx[R];
    tp[p] = tail_table + (size_t)trow * DD;
    biasv[p] = rel_bias[trow];     // 16 lanes same addr -> broadcast
  }
  f4 ha[4], hb[4], ta[4], tb[4];
  #pragma unroll
  for (int p = 0; p < 4; ++p) {
    // unconditional: offsets stay inside the table (junk redirected in-row)
    ha[p] = *(const f4*)(hp[p] + aoff);
    hb[p] = *(const f4*)(hp[p] + boff);
    ta[p] = *(const f4*)(tp[p] + aoff);
    tb[p] = *(const f4*)(tp[p] + boff);
  }

  float pos_acc = 0.f;
  #pragma unroll
  for (int p = 0; p < 4; ++p) {
    f4 e0 = ha[p] + ra, e1 = hb[p] + rb;
    if (kg > 12)  e0 = (f4){0.f,0.f,0.f,0.f};   // mask junk lanes
    if (kg >= 12) e1 = (f4){0.f,0.f,0.f,0.f};
    exA4[(p * 4 + (kg >> 2)) * 64 + rid + 16 * (kg & 3)] = pack8(e0, e1);
    // fp32 pos dot; e masked zero kills junk t contributions
    float d = e0[0]*ta[p][0] + e0[1]*ta[p][1] + e0[2]*ta[p][2] + e0[3]*ta[p][3]
            + e1[0]*tb[p][0] + e1[1]*tb[p][1] + e1[2]*tb[p][2] + e1[3]*tb[p][3];
    d += __shfl_xor(d, 1); d += __shfl_xor(d, 2);
    d += __shfl_xor(d, 4); d += __shfl_xor(d, 8);
    if (kg == 0) {
      bias_s[p * 16 + rid] = biasv[p];
      pos_acc += softplus_full(-(d + biasv[p]));   // -log_sigmoid(pos_logit)
    }
  }
  __syncthreads();

  // ---- neg matmul: 2 mf-halves outer (32-VGPR A-frags), 8 s-groups inner ----
  const int w = t >> 6, lane = t & 63, quad = lane >> 4;
  const short8* exAs = (const short8*)exA4;
  const short8* nf   = (const short8*)nws;
  float nacc = 0.f;
  #pragma unroll
  for (int h = 0; h < 2; ++h) {
    short8 afr[2][4];
    float  br[2][4];
    #pragma unroll
    for (int m = 0; m < 2; ++m) {
      int mf = h * 2 + m;
      #pragma unroll
      for (int ks = 0; ks < 4; ++ks) afr[m][ks] = exAs[(mf * 4 + ks) * 64 + lane];
      #pragma unroll
      for (int r = 0; r < 4; ++r)   br[m][r]  = bias_s[mf * 16 + quad * 4 + r];
    }
    #pragma unroll 2
    for (int g = 0; g < 8; ++g) {
      int ng = w * 8 + g;
      short8 bfr[4];
      #pragma unroll
      for (int ks = 0; ks < 4; ++ks)
        bfr[ks] = nf[(ng * 4 + ks) * 64 + lane];   // L2-hot
      floatx4 acc[2];
      #pragma unroll
      for (int m = 0; m < 2; ++m) {                // bias folded into C-init
        floatx4 c; c[0]=br[m][0]; c[1]=br[m][1]; c[2]=br[m][2]; c[3]=br[m][3];
        acc[m] = c;
      }
      #pragma unroll
      for (int ks = 0; ks < 4; ++ks)
        #pragma unroll
        for (int m = 0; m < 2; ++m)
          acc[m] = __builtin_amdgcn_mfma_f32_16x16x32_bf16(afr[m][ks], bfr[ks], acc[m], 0, 0, 0);
      // per-group guarded epilogue (8 logits/lane)
      float s1 = 0.f, s2 = 0.f, gmax = 0.f;
      #pragma unroll
      for (int m = 0; m < 2; ++m)
        #pragma unroll
        for (int r = 0; r < 4; ++r) {
          float x = acc[m][r];
          s1 += x;
          s2 = fmaf(x, x, s2);
          gmax = fmaxf(gmax, fabsf(x));            // fabs = input modifier
        }
      if (__ballot(gmax < 0.03f) == ~0ULL) {
        // deg-2 Taylor softplus: ln2 + x/2 + x^2/8, |err|<5e-9 for |x|<0.03
        nacc += fmaf(s1, 0.5f, fmaf(s2, 0.125f, 8.f * LN2F));
      } else {                                     // inline exact path, no scratch
        #pragma unroll
        for (int m = 0; m < 2; ++m)
          #pragma unroll
          for (int r = 0; r < 4; ++r)
            nacc += softplus_full(acc[m][r]);
      }
    }
  }

  // ---- block reduce -> atomic accumulate (exact pow2 1/BB scale) ----
  float tot = nacc + pos_acc;
  #pragma unroll
  for (int off = 32; off; off >>= 1) tot += __shfl_down(tot, off);
  if (lane == 0) red[w] = tot;
  __syncthreads();
  if (t == 0)
    atomicAdd(out, (red[0] + red[1] + red[2] + red[3]) * (1.0f / (float)BB));
}

extern "C" void kernel_launch(void* const* d_in, const int* in_sizes, int n_in,
                              void* d_out, int out_size, void* d_ws, size_t ws_size,
                              hipStream_t stream) {
  const float* head_table = (const float*)d_in[0];
  const float* tail_table = (const float*)d_in[1];
  const float* rel_vec    = (const float*)d_in[2];
  const float* rel_bias   = (const float*)d_in[3];
  const int*   head_idx   = (const int*)d_in[4];
  const int*   tail_idx   = (const int*)d_in[5];
  const int*   neg_idx    = (const int*)d_in[6];
  float* out = (float*)d_out;

  u32x4* nws = (u32x4*)d_ws;                 // 512 x 128 bf16 = 131072 B

  negprep_k<<<32, 256, 0, stream>>>(tail_table, neg_idx, nws, out);
  keg_main<<<1024, 256, 0, stream>>>(head_table, tail_table, rel_vec, rel_bias,
                                     head_idx, tail_idx, (const u32x4*)nws, out);
}